// Round 9
// baseline (325.700 us; speedup 1.0000x reference)
//
#include <hip/hip_runtime.h>
#include <stdint.h>

// QNetSNN: B=16384, HIDDEN=64, T=40. Wave=row, lane=neuron.
// R9: pair stream (zsm -> {Warec, Wcin1}) served by an L2-resident BYTE-LUT:
// pA/pC = sum over 8 bytes of LUT[pos][byte][lane] (double2, f64-precomputed).
// All 8 addresses derive in parallel from the wave-uniform mask -> no serial
// ctz->load chain (R8's failure mode), fixed 8 loads vs ~19. wsrec LDS stream
// drops to f32+cvt (exact). fold stays f64 LDS. Fallback = proven R4.
//
// ws map (as double*): lutP double2[8*256*64] = 2 MB @ 0
//                      wsin32 f32[3072] @ f32-idx 524288 | wain32 f32[512] after
// LDS 48 KB: wsrecL f32[4096] [k][n] | foldL f64[4096] [k][n]

__device__ __forceinline__ uint64_t rfl64(uint64_t x) {
    uint32_t lo = (uint32_t)__builtin_amdgcn_readfirstlane((int)(uint32_t)(x & 0xFFFFFFFFull));
    uint32_t hi = (uint32_t)__builtin_amdgcn_readfirstlane((int)(uint32_t)(x >> 32));
    return ((uint64_t)hi << 32) | (uint64_t)lo;
}

// ======================= R9 fast path =======================

__global__ void snn_prep9(const float* __restrict__ Warec, const float* __restrict__ Wcin,
                          const float* __restrict__ Wsin, const float* __restrict__ Wain,
                          double* __restrict__ ws) {
    int tid = blockIdx.x * 256 + threadIdx.x;      // 0 .. 134655
    if (tid < 131072) {
        // tid = (pos<<14) | (val<<6) | lane  ->  double2 index == tid
        int lane = tid & 63;
        int val  = (tid >> 6) & 255;
        int pos  = tid >> 14;                       // 0..7
        double sA = 0.0, sC = 0.0;
        for (int j = 0; j < 8; ++j) {
            if (val & (1 << j)) {
                int k = (pos << 3) + j;
                sA += (double)Warec[lane * 64 + k];
                sC += (double)Wcin[lane * 128 + k];
            }
        }
        ws[2 * tid]     = sA;
        ws[2 * tid + 1] = sC;
    } else if (tid < 131072 + 3072) {
        int r = tid - 131072; int k = r >> 6, n = r & 63;
        ((float*)(ws + 262144))[r] = Wsin[n * 48 + k];
    } else if (tid < 131072 + 3584) {
        int r = tid - 131072 - 3072; int k = r >> 6, n = r & 63;
        ((float*)(ws + 262144))[3072 + r] = Wain[n * 8 + k];
    }
}

__launch_bounds__(1024, 4)
__global__ void snn_main9(const float* __restrict__ state, const float* __restrict__ action,
                          const float* __restrict__ Wsrec, const float* __restrict__ Wcin,
                          const float* __restrict__ Wcrec, const float* __restrict__ Wro,
                          const double* __restrict__ ws, float* __restrict__ out) {
    __shared__ float  wsrecL[4096];   // [k<<6|n] f32 (exact; cvt on use), 16 KB
    __shared__ double foldL[4096];    // [k<<6|n] f64 = Wcin[:,64:]+Wcrec, 32 KB

    const int tid = threadIdx.x;
    for (int e = tid; e < 8192; e += 1024) {
        if (e < 4096) {
            int k = e >> 6, n = e & 63;
            wsrecL[e] = Wsrec[n * 64 + k];
        } else {
            int r = e - 4096; int k = r >> 6, n = r & 63;
            foldL[r] = (double)Wcin[n * 128 + 64 + k] + (double)Wcrec[n * 64 + k];
        }
    }
    __syncthreads();

    const int lane = tid & 63;
    const int wave = tid >> 6;
    const int row  = blockIdx.x * 16 + wave;

    double cur = 0.0;
    if (lane < 24)      cur = fmax( 50.0 * (double)state[row * 24 + lane], 0.0);
    else if (lane < 48) cur = fmax(-50.0 * (double)state[row * 24 + lane - 24], 0.0);
    else if (lane < 52) cur = fmax( 50.0 * (double)action[row * 4 + lane - 48], 0.0);
    else if (lane < 56) cur = fmax(-50.0 * (double)action[row * 4 + lane - 52], 0.0);

    // Always-on lanes: venc = 0.1*cur bit-identically each step -> exact predicate.
    double v1 = 0.0 + 0.1 * (cur - 0.0);
    bool alw = (v1 - 1.0) > 0.0;
    double curv = alw ? 0.0 : cur;
    uint64_t AM = rfl64(__ballot(alw));

    const double2* __restrict__ lutP  = (const double2*)ws;
    const float*  __restrict__ wsin32 = (const float*)(ws + 262144);
    const float*  __restrict__ wain32 = wsin32 + 3072;
    const float wro = Wro[lane];

    double Ssin = 0.0, Sain = 0.0;
    {
        uint64_t m = AM & 0x0000FFFFFFFFFFFFull;
        while (m) { int k = __builtin_ctzll(m); m &= m - 1; Ssin += (double)wsin32[(k << 6) + lane]; }
        m = AM >> 48;
        while (m) { int k = __builtin_ctzll(m); m &= m - 1; Sain += (double)wain32[(k << 6) + lane]; }
    }

    double venc = 0.0, v = 0.0, icur = 0.0, vli = 0.0, ili = 0.0, vmax = 0.0;
    uint64_t zmask = 0;  // z_c of previous step

    for (int t = 0; t < 40; ++t) {
        // ---- layer-s threshold (entering v,i only) ----
        double vd = v + 0.1 * (icur - v);
        bool zs = (vd - 1.0) > 0.0;
        double vs_new = zs ? 0.0 : vd;
        uint64_t zsm = rfl64(__ballot(zs));

        // ---- pair via byte-LUT (L2, double2): 8 parallel lookups, no ctz chain ----
        double pA0 = 0.0, pA1 = 0.0, pC0 = 0.0, pC1 = 0.0;
        {
            #pragma unroll
            for (int b = 0; b < 8; b += 2) {
                uint32_t v0 = (uint32_t)(zsm >> (b << 3)) & 0xFFu;
                uint32_t v1 = (uint32_t)(zsm >> ((b + 1) << 3)) & 0xFFu;
                double2 e0 = lutP[(((b << 8) | v0) << 6) + lane];
                double2 e1 = lutP[((((b + 1) << 8) | v1) << 6) + lane];
                pA0 += e0.x; pC0 += e0.y;
                pA1 += e1.x; pC1 += e1.y;
            }
        }

        // ---- encoder (variable lanes only) ----
        venc = venc + 0.1 * (curv - venc);
        bool esp = (venc - 1.0) > 0.0;
        venc = esp ? 0.0 : venc;
        uint64_t em = rfl64(__ballot(esp));

        // ---- layer s: zmask -> wsrecL (LDS f32, exact cvt), R4 2-wide shape ----
        double acc = (icur - 0.2 * icur) + Ssin;
        {
            uint64_t m = em & 0x0000FFFFFFFFFFFFull;
            while (m) { int k = __builtin_ctzll(m); m &= m - 1; acc += (double)wsin32[(k << 6) + lane]; }
            double a0 = 0.0, a1 = 0.0;
            m = zmask;
            while (m) {
                int k = __builtin_ctzll(m); m &= m - 1; a0 += (double)wsrecL[(k << 6) + lane];
                if (m) { k = __builtin_ctzll(m); m &= m - 1; a1 += (double)wsrecL[(k << 6) + lane]; }
            }
            acc += a0 + a1;
        }
        double icur_s = acc;

        // ---- layer a ----
        vd = vs_new + 0.1 * (icur_s - vs_new);
        bool za = (vd - 1.0) > 0.0;
        double va_new = za ? 0.0 : vd;
        uint64_t zam = rfl64(__ballot(za));

        acc = (icur_s - 0.2 * icur_s) + Sain + ((pA0 + pA1));
        {
            uint64_t m = (em >> 48);
            while (m) { int k = __builtin_ctzll(m); m &= m - 1; acc += (double)wain32[(k << 6) + lane]; }
        }
        double icur_a = acc;

        // ---- layer c: zam -> foldL (LDS f64), R4 2-wide shape ----
        vd = va_new + 0.1 * (icur_a - va_new);
        bool zc = (vd - 1.0) > 0.0;
        v = zc ? 0.0 : vd;
        zmask = rfl64(__ballot(zc));

        double f0 = 0.0, f1 = 0.0;
        {
            uint64_t m = zam;
            while (m) {
                int k = __builtin_ctzll(m); m &= m - 1; f0 += foldL[(k << 6) + lane];
                if (m) { k = __builtin_ctzll(m); m &= m - 1; f1 += foldL[(k << 6) + lane]; }
            }
        }
        icur = (icur_a - 0.2 * icur_a) + (pC0 + pC1) + (f0 + f1);

        // ---- LI readout (feed-forward -> f32 reduce safe) ----
        float p = zc ? wro : 0.f;
        #pragma unroll
        for (int off = 32; off >= 1; off >>= 1) p += __shfl_xor(p, off, 64);
        double vnew = vli + 0.1 * (ili - vli);
        ili = (ili - 0.2 * ili) + (double)p;
        vli = vnew;
        vmax = fmax(vmax, vli);
    }

    if (lane == 0) out[row] = (float)vmax;
}

// ======================= R4 fallback (proven, 204 us) =======================

__global__ void snn_prep4(const float* __restrict__ Wsin, const float* __restrict__ Wain,
                          const float* __restrict__ Warec, const float* __restrict__ Wcin,
                          float* __restrict__ ws) {
    int tid = blockIdx.x * 256 + threadIdx.x;
    if (tid < 3072) {
        int k = tid >> 6, n = tid & 63;
        ws[tid] = Wsin[n * 48 + k];
    } else if (tid < 3584) {
        int r = tid - 3072; int k = r >> 6, n = r & 63;
        ws[tid] = Wain[n * 8 + k];
    } else if (tid < 11776) {
        int r = tid - 3584; int k = r >> 7; int rem = r & 127; int n = rem >> 1;
        ws[tid] = (rem & 1) ? Wcin[n * 128 + k] : Warec[n * 64 + k];
    }
}

__launch_bounds__(1024, 4)
__global__ void snn_main4(const float* __restrict__ state, const float* __restrict__ action,
                          const float* __restrict__ Wsrec, const float* __restrict__ Wcin,
                          const float* __restrict__ Wcrec, const float* __restrict__ Wro,
                          const float* __restrict__ ws, float* __restrict__ out) {
    __shared__ double lds[8192];
    const int tid = threadIdx.x;
    for (int e = tid; e < 8192; e += 1024) {
        int half = e >> 12; int sub = e & 4095; int k = sub >> 6; int n = sub & 63;
        double val;
        if (half == 0) val = (double)Wsrec[n * 64 + k];
        else           val = (double)Wcin[n * 128 + 64 + k] + (double)Wcrec[n * 64 + k];
        lds[e] = val;
    }
    __syncthreads();
    const int lane = tid & 63; const int wave = tid >> 6; const int row = blockIdx.x * 16 + wave;
    double cur = 0.0;
    if (lane < 24)      cur = fmax( 50.0 * (double)state[row * 24 + lane], 0.0);
    else if (lane < 48) cur = fmax(-50.0 * (double)state[row * 24 + lane - 24], 0.0);
    else if (lane < 52) cur = fmax( 50.0 * (double)action[row * 4 + lane - 48], 0.0);
    else if (lane < 56) cur = fmax(-50.0 * (double)action[row * 4 + lane - 52], 0.0);
    double v1 = 0.0 + 0.1 * (cur - 0.0);
    bool alw = (v1 - 1.0) > 0.0;
    double curv = alw ? 0.0 : cur;
    uint64_t AM = rfl64(__ballot(alw));
    const float*  __restrict__ wsin32 = ws;
    const float*  __restrict__ wain32 = ws + 3072;
    const float2* __restrict__ pair   = (const float2*)(ws + 3584);
    const float wro = Wro[lane];
    double Ssin = 0.0, Sain = 0.0;
    {
        uint64_t m = AM & 0x0000FFFFFFFFFFFFull;
        while (m) { int k = __builtin_ctzll(m); m &= m - 1; Ssin += (double)wsin32[(k << 6) + lane]; }
        m = AM >> 48;
        while (m) { int k = __builtin_ctzll(m); m &= m - 1; Sain += (double)wain32[(k << 6) + lane]; }
    }
    double venc = 0.0, v = 0.0, icur = 0.0, vli = 0.0, ili = 0.0, vmax = 0.0;
    uint64_t zmask = 0;
    for (int t = 0; t < 40; ++t) {
        double vd = v + 0.1 * (icur - v);
        bool zs = (vd - 1.0) > 0.0;
        double vs_new = zs ? 0.0 : vd;
        uint64_t zsm = rfl64(__ballot(zs));
        double pA0 = 0.0, pA1 = 0.0, pC0 = 0.0, pC1 = 0.0;
        {
            uint64_t m = zsm;
            while (m) {
                int k = __builtin_ctzll(m); m &= m - 1;
                float2 w = pair[(k << 6) + lane];
                pA0 += (double)w.x; pC0 += (double)w.y;
                if (m) {
                    k = __builtin_ctzll(m); m &= m - 1;
                    float2 u = pair[(k << 6) + lane];
                    pA1 += (double)u.x; pC1 += (double)u.y;
                }
            }
        }
        venc = venc + 0.1 * (curv - venc);
        bool esp = (venc - 1.0) > 0.0;
        venc = esp ? 0.0 : venc;
        uint64_t em = rfl64(__ballot(esp));
        double acc = (icur - 0.2 * icur) + Ssin;
        {
            uint64_t m = em & 0x0000FFFFFFFFFFFFull;
            while (m) { int k = __builtin_ctzll(m); m &= m - 1; acc += (double)wsin32[(k << 6) + lane]; }
            double a0 = 0.0, a1 = 0.0;
            m = zmask;
            while (m) {
                int k = __builtin_ctzll(m); m &= m - 1; a0 += lds[(k << 6) + lane];
                if (m) { k = __builtin_ctzll(m); m &= m - 1; a1 += lds[(k << 6) + lane]; }
            }
            acc += a0 + a1;
        }
        double icur_s = acc;
        vd = vs_new + 0.1 * (icur_s - vs_new);
        bool za = (vd - 1.0) > 0.0;
        double va_new = za ? 0.0 : vd;
        uint64_t zam = rfl64(__ballot(za));
        acc = (icur_s - 0.2 * icur_s) + Sain + (pA0 + pA1);
        {
            uint64_t m = (em >> 48);
            while (m) { int k = __builtin_ctzll(m); m &= m - 1; acc += (double)wain32[(k << 6) + lane]; }
        }
        double icur_a = acc;
        vd = va_new + 0.1 * (icur_a - va_new);
        bool zc = (vd - 1.0) > 0.0;
        v = zc ? 0.0 : vd;
        zmask = rfl64(__ballot(zc));
        double f0 = 0.0, f1 = 0.0;
        {
            uint64_t m = zam;
            while (m) {
                int k = __builtin_ctzll(m); m &= m - 1;
                f0 += lds[4096 + (k << 6) + lane];
                if (m) { k = __builtin_ctzll(m); m &= m - 1; f1 += lds[4096 + (k << 6) + lane]; }
            }
        }
        icur = (icur_a - 0.2 * icur_a) + (pC0 + pC1) + (f0 + f1);
        float p = zc ? wro : 0.f;
        #pragma unroll
        for (int off = 32; off >= 1; off >>= 1) p += __shfl_xor(p, off, 64);
        double vnew = vli + 0.1 * (ili - vli);
        ili = (ili - 0.2 * ili) + (double)p;
        vli = vnew;
        vmax = fmax(vmax, vli);
    }
    if (lane == 0) out[row] = (float)vmax;
}

extern "C" void kernel_launch(void* const* d_in, const int* in_sizes, int n_in,
                              void* d_out, int out_size, void* d_ws, size_t ws_size,
                              hipStream_t stream) {
    const float* state  = (const float*)d_in[0];
    const float* action = (const float*)d_in[1];
    const float* Wsin   = (const float*)d_in[2];
    const float* Wsrec  = (const float*)d_in[3];
    const float* Wain   = (const float*)d_in[4];
    const float* Warec  = (const float*)d_in[5];
    const float* Wcin   = (const float*)d_in[6];
    const float* Wcrec  = (const float*)d_in[7];
    const float* Wro    = (const float*)d_in[8];
    float* out = (float*)d_out;
    const int B = in_sizes[0] / 24;  // 16384

    const size_t need9 = 262144ull * 8 + 3584ull * 4;   // LUT 2MB + wsin/wain 14KB
    if (ws_size >= need9) {
        double* ws = (double*)d_ws;
        snn_prep9<<<527, 256, 0, stream>>>(Warec, Wcin, Wsin, Wain, ws);
        snn_main9<<<B / 16, 1024, 0, stream>>>(state, action, Wsrec, Wcin, Wcrec, Wro, ws, out);
    } else {
        float* ws = (float*)d_ws;
        snn_prep4<<<46, 256, 0, stream>>>(Wsin, Wain, Warec, Wcin, ws);
        snn_main4<<<B / 16, 1024, 0, stream>>>(state, action, Wsrec, Wcin, Wcrec, Wro, ws, out);
    }
}